// Round 2
// baseline (3179.048 us; speedup 1.0000x reference)
//
#include <hip/hip_runtime.h>
#include <hip/hip_bf16.h>

typedef unsigned short u16;
typedef unsigned int u32;

#define SCALE2 0.08838834764831845f
#define LNEPS 1e-5f

__device__ __forceinline__ float b2f(u16 u) {
  return __uint_as_float(((u32)u) << 16);
}
__device__ __forceinline__ u16 f2b(float f) {
  u32 x = __float_as_uint(f);
  return (u16)((x + 0x7fffu + ((x >> 16) & 1u)) >> 16);  // RNE
}
__device__ __forceinline__ float2 upk(u32 u) {
  return make_float2(__uint_as_float(u << 16), __uint_as_float(u & 0xffff0000u));
}
__device__ __forceinline__ u32 pk2(float lo, float hi) {
  return (u32)f2b(lo) | ((u32)f2b(hi) << 16);
}
__device__ __forceinline__ float ldf(const float* p) { return *p; }
__device__ __forceinline__ float ldf(const u16* p) { return b2f(*p); }
__device__ __forceinline__ void stf(float* p, float v) { *p = v; }
__device__ __forceinline__ void stf(u16* p, float v) { *p = f2b(v); }

// ---------------- GEMM: out[m][n] = sum_k X[m][k]*W[n][k] + bias[n]; K=384 fixed
template <typename TX, typename TO>
__global__ __launch_bounds__(256) void gemm_bias(
    const TX* __restrict__ X, const float* __restrict__ W,
    const float* __restrict__ bias, TO* __restrict__ out, int N) {
  __shared__ float As[32][68];
  __shared__ float Bs[32][68];
  const int tid = threadIdx.x;
  const int tx = tid & 15, ty = tid >> 4;
  const int m0 = blockIdx.y * 64, n0 = blockIdx.x * 64;
  float acc[4][4] = {};
  for (int kt = 0; kt < 384; kt += 32) {
#pragma unroll
    for (int i = 0; i < 8; ++i) {
      int e = tid + i * 256;
      int m = e >> 5, k = e & 31;
      As[k][m] = ldf(&X[(size_t)(m0 + m) * 384 + kt + k]);
    }
#pragma unroll
    for (int i = 0; i < 8; ++i) {
      int e = tid + i * 256;
      int nn = e >> 5, k = e & 31;
      Bs[k][nn] = W[(size_t)(n0 + nn) * 384 + kt + k];
    }
    __syncthreads();
#pragma unroll
    for (int kk = 0; kk < 32; ++kk) {
      float4 av = *(const float4*)&As[kk][ty * 4];
      float4 bv = *(const float4*)&Bs[kk][tx * 4];
      acc[0][0] += av.x * bv.x; acc[0][1] += av.x * bv.y; acc[0][2] += av.x * bv.z; acc[0][3] += av.x * bv.w;
      acc[1][0] += av.y * bv.x; acc[1][1] += av.y * bv.y; acc[1][2] += av.y * bv.z; acc[1][3] += av.y * bv.w;
      acc[2][0] += av.z * bv.x; acc[2][1] += av.z * bv.y; acc[2][2] += av.z * bv.z; acc[2][3] += av.z * bv.w;
      acc[3][0] += av.w * bv.x; acc[3][1] += av.w * bv.y; acc[3][2] += av.w * bv.z; acc[3][3] += av.w * bv.w;
    }
    __syncthreads();
  }
#pragma unroll
  for (int r = 0; r < 4; ++r) {
    int m = m0 + ty * 4 + r;
#pragma unroll
    for (int c = 0; c < 4; ++c) {
      int nn = n0 + tx * 4 + c;
      stf(&out[(size_t)m * N + nn], acc[r][c] + bias[nn]);
    }
  }
}

// ---------------- row LayerNorm, in place (templated storage)
template <typename T>
__global__ __launch_bounds__(256) void ln_inplace(
    T* __restrict__ Tb, const float* __restrict__ w, const float* __restrict__ b, int N) {
  const int row = blockIdx.x, tid = threadIdx.x;
  T* Tr = Tb + (size_t)row * N;
  float vals[3];
  float s = 0.f, ss = 0.f;
  int nv = 0;
  for (int i = tid; i < N; i += 256) {
    float v = ldf(&Tr[i]);
    vals[nv++] = v;
    s += v; ss += v * v;
  }
#pragma unroll
  for (int mk = 32; mk; mk >>= 1) { s += __shfl_xor(s, mk); ss += __shfl_xor(ss, mk); }
  __shared__ float red[8];
  if ((tid & 63) == 0) { red[tid >> 6] = s; red[4 + (tid >> 6)] = ss; }
  __syncthreads();
  s = red[0] + red[1] + red[2] + red[3];
  ss = red[4] + red[5] + red[6] + red[7];
  float inv = 1.f / (float)N;
  float mean = s * inv;
  float var = fmaxf(ss * inv - mean * mean, 0.f);
  float rstd = rsqrtf(var + LNEPS);
  nv = 0;
  for (int i = tid; i < N; i += 256) {
    float v = (vals[nv++] - mean) * rstd * w[i] + b[i];
    stf(&Tr[i], v);
  }
}

// ---------------- LN over split storage: lo = f32 chans 0..383, hi = bf16 chans 384..767
__global__ __launch_bounds__(256) void ln_wf_split(
    float* __restrict__ lo, u16* __restrict__ hi,
    const float* __restrict__ w, const float* __restrict__ b) {
  const int row = blockIdx.x, tid = threadIdx.x;
  float* L = lo + (size_t)row * 384;
  u16* H = hi + (size_t)row * 384;
  float vals[3];
  float s = 0.f, ss = 0.f;
  int nv = 0;
  for (int i = tid; i < 768; i += 256) {
    float v = (i < 384) ? L[i] : b2f(H[i - 384]);
    vals[nv++] = v;
    s += v; ss += v * v;
  }
#pragma unroll
  for (int mk = 32; mk; mk >>= 1) { s += __shfl_xor(s, mk); ss += __shfl_xor(ss, mk); }
  __shared__ float red[8];
  if ((tid & 63) == 0) { red[tid >> 6] = s; red[4 + (tid >> 6)] = ss; }
  __syncthreads();
  s = red[0] + red[1] + red[2] + red[3];
  ss = red[4] + red[5] + red[6] + red[7];
  float mean = s * (1.f / 768.f);
  float var = fmaxf(ss * (1.f / 768.f) - mean * mean, 0.f);
  float rstd = rsqrtf(var + LNEPS);
  nv = 0;
  for (int i = tid; i < 768; i += 256) {
    float v = (vals[nv++] - mean) * rstd * w[i] + b[i];
    if (i < 384) L[i] = v; else H[i - 384] = f2b(v);
  }
}

// ---------------- DWT sf: t_sf f32 (B,4096,384) -> q1 f32 (B,1024,384), q2 bf16 (B*3,1024,384)
__global__ __launch_bounds__(256) void dwt_sf(
    const float* __restrict__ T, float* __restrict__ q1, u16* __restrict__ q2) {
  const int blk = blockIdx.x;
  const int b = blk >> 10, pos = blk & 1023;
  const int i = pos >> 5, j = pos & 31;
  const int p00 = (i * 2) * 64 + j * 2;
  const float* base = T + (size_t)b * 4096 * 384;
  for (int ch = threadIdx.x; ch < 384; ch += 256) {
    float a  = base[(size_t)p00 * 384 + ch];         // even row, even col
    float cc = base[(size_t)(p00 + 1) * 384 + ch];   // even row, odd col
    float bb = base[(size_t)(p00 + 64) * 384 + ch];  // odd row, even col
    float dd = base[(size_t)(p00 + 65) * 384 + ch];  // odd row, odd col
    float s0 = 0.5f * ( a + bb + cc + dd);
    float s1 = 0.5f * (-a - bb + cc + dd);
    float s2 = 0.5f * (-a + bb - cc + dd);
    float s3 = 0.5f * ( a - bb - cc + dd);
    q1[(size_t)(b * 1024 + pos) * 384 + ch] = s0;
    q2[(size_t)((b * 3 + 0) * 1024 + pos) * 384 + ch] = f2b(s1);
    q2[(size_t)((b * 3 + 1) * 1024 + pos) * 384 + ch] = f2b(s2);
    q2[(size_t)((b * 3 + 2) * 1024 + pos) * 384 + ch] = f2b(s3);
  }
}

// ---------------- DWT wf (split input): lo f32 chans 0..383, hi bf16 chans 384..767
//  -> k1 f32, v1 bf16, k2/v2 bf16 (B*3,1024,384)
__global__ __launch_bounds__(256) void dwt_wf_split(
    const float* __restrict__ lo, const u16* __restrict__ hi,
    float* __restrict__ k1, u16* __restrict__ k2,
    u16* __restrict__ v1, u16* __restrict__ v2) {
  const int blk = blockIdx.x;
  const int b = blk >> 10, pos = blk & 1023;
  const int i = pos >> 5, j = pos & 31;
  const int p00 = (i * 2) * 64 + j * 2;
  for (int ch = threadIdx.x; ch < 768; ch += 256) {
    float a, bb, cc, dd;
    if (ch < 384) {
      const float* base = lo + (size_t)b * 4096 * 384;
      a  = base[(size_t)p00 * 384 + ch];
      cc = base[(size_t)(p00 + 1) * 384 + ch];
      bb = base[(size_t)(p00 + 64) * 384 + ch];
      dd = base[(size_t)(p00 + 65) * 384 + ch];
    } else {
      const u16* base = hi + (size_t)b * 4096 * 384;
      int c = ch - 384;
      a  = b2f(base[(size_t)p00 * 384 + c]);
      cc = b2f(base[(size_t)(p00 + 1) * 384 + c]);
      bb = b2f(base[(size_t)(p00 + 64) * 384 + c]);
      dd = b2f(base[(size_t)(p00 + 65) * 384 + c]);
    }
    float s0 = 0.5f * ( a + bb + cc + dd);
    float s1 = 0.5f * (-a - bb + cc + dd);
    float s2 = 0.5f * (-a + bb - cc + dd);
    float s3 = 0.5f * ( a - bb - cc + dd);
    if (ch < 384) {
      size_t po = (size_t)(b * 1024 + pos) * 384 + ch;
      k1[po] = s0;
      v1[po] = f2b(s2);
      k2[(size_t)((b * 3 + 1) * 1024 + pos) * 384 + ch] = f2b(s1);
      v2[(size_t)((b * 3 + 1) * 1024 + pos) * 384 + ch] = f2b(s3);
    } else {
      int c = ch - 384;
      k2[(size_t)((b * 3 + 0) * 1024 + pos) * 384 + c] = f2b(s0);
      k2[(size_t)((b * 3 + 2) * 1024 + pos) * 384 + c] = f2b(s1);
      v2[(size_t)((b * 3 + 0) * 1024 + pos) * 384 + c] = f2b(s2);
      v2[(size_t)((b * 3 + 2) * 1024 + pos) * 384 + c] = f2b(s3);
    }
  }
}

// ---------------- att1: single-pass online-softmax flash, f32 q/k, bf16 v, scale=1
// grid (64, 8): 16-row query tile per block. Writes xall chans 0..383.
__global__ __launch_bounds__(256) void flash_att1(
    const float* __restrict__ q, const float* __restrict__ k,
    const u16* __restrict__ v, u16* __restrict__ xall) {
  __shared__ float Qs[16 * 388];
  __shared__ float Ks[16 * 388];
  __shared__ u32 Vs[16 * 192];
  __shared__ float Ps[16 * 17];
  __shared__ float Ps2[16 * 17];
  const int tid = threadIdx.x;
  const int r = tid & 15, sg = tid >> 4;  // r = own row; sg = stream row / col-group
  const int b = blockIdx.y, o0 = blockIdx.x * 16;
  {
    const float4* src = (const float4*)(q + ((size_t)b * 1024 + o0) * 384);
    for (int i = tid; i < 16 * 96; i += 256) {
      int rr = i / 96, cc = i % 96;
      *(float4*)&Qs[rr * 388 + cc * 4] = src[(size_t)rr * 96 + cc];
    }
  }
  float m_r = -1e30f, l_r = 0.f;
  float acc[24] = {};
  for (int st = 0; st < 64; ++st) {
    __syncthreads();
    {
      const float4* src = (const float4*)(k + ((size_t)b * 1024 + st * 16) * 384);
      for (int i = tid; i < 16 * 96; i += 256) {
        int rr = i / 96, cc = i % 96;
        *(float4*)&Ks[rr * 388 + cc * 4] = src[(size_t)rr * 96 + cc];
      }
      const uint2* vsrc = (const uint2*)(v + ((size_t)b * 1024 + st * 16) * 384);
      for (int i = tid; i < 16 * 96; i += 256) {
        int rr = i / 96, cc = i % 96;
        *(uint2*)&Vs[rr * 192 + cc * 2] = vsrc[(size_t)rr * 96 + cc];
      }
    }
    __syncthreads();
    // raw score d(r, sg)
    float d = 0.f;
    {
      const float* qa = &Qs[r * 388];
      const float* ka = &Ks[sg * 388];
#pragma unroll 4
      for (int kk = 0; kk < 96; ++kk) {
        float4 a = *(const float4*)&qa[kk * 4];
        float4 bb = *(const float4*)&ka[kk * 4];
        d += a.x * bb.x + a.y * bb.y + a.z * bb.z + a.w * bb.w;
      }
    }
    Ps[r * 17 + sg] = d;
    __syncthreads();
    float rowmax = -1e30f;
#pragma unroll
    for (int s2 = 0; s2 < 16; ++s2) rowmax = fmaxf(rowmax, Ps[r * 17 + s2]);
    float nm = fmaxf(m_r, rowmax);
    float alpha = __expf(m_r - nm);
    m_r = nm;
#pragma unroll
    for (int c = 0; c < 24; ++c) acc[c] *= alpha;
    Ps2[r * 17 + sg] = __expf(d - nm);
    __syncthreads();
    float sume = 0.f;
#pragma unroll
    for (int s2 = 0; s2 < 16; ++s2) sume += Ps2[r * 17 + s2];
    l_r = l_r * alpha + sume;
#pragma unroll 1
    for (int s2 = 0; s2 < 16; ++s2) {
      float pp = Ps2[r * 17 + s2];
      const u32* vr = &Vs[s2 * 192 + sg * 12];
#pragma unroll
      for (int ii = 0; ii < 12; ++ii) {
        float2 vf = upk(vr[ii]);
        acc[2 * ii]     += pp * vf.x;
        acc[2 * ii + 1] += pp * vf.y;
      }
    }
  }
  float invl = 1.f / l_r;
  u32* outU = (u32*)xall;
  size_t base = ((size_t)(b * 1024 + o0 + r)) * 768 + sg * 12;
#pragma unroll
  for (int ii = 0; ii < 12; ++ii) {
    outU[base + ii] = pk2(acc[2 * ii] * invl, acc[2 * ii + 1] * invl);
  }
}

// ---------------- att2 stats: per query row, running max & sumexp over all keys (bf16)
__global__ __launch_bounds__(256) void att_stats(
    const u16* __restrict__ q, const u16* __restrict__ k,
    float2* __restrict__ stats, float scale) {
  __shared__ u16 Qs[32 * 386];  // row stride 193 uints (odd -> conflict-free)
  __shared__ u16 Ks[32 * 386];
  const int tid = threadIdx.x;
  const int tx = tid & 15, ty = tid >> 4;
  const int bh = blockIdx.y, o0 = blockIdx.x * 32;
  {
    const uint2* src = (const uint2*)(q + ((size_t)bh * 1024 + o0) * 384);
    u32* dst = (u32*)Qs;
#pragma unroll
    for (int i = 0; i < 12; ++i) {
      int e = tid + i * 256;
      int r = e / 96, c8 = e % 96;
      uint2 v = src[e];
      dst[r * 193 + c8 * 2] = v.x;
      dst[r * 193 + c8 * 2 + 1] = v.y;
    }
  }
  const int r0 = ty * 2, r1 = r0 + 1, s0 = tx * 2, s1 = s0 + 1;
  float m0 = -1e30f, m1 = -1e30f, l0 = 0.f, l1 = 0.f;
  const u32* QsU = (const u32*)Qs;
  const u32* KsU = (const u32*)Ks;
  for (int st = 0; st < 32; ++st) {
    __syncthreads();
    {
      const uint2* src = (const uint2*)(k + ((size_t)bh * 1024 + st * 32) * 384);
      u32* dst = (u32*)Ks;
#pragma unroll
      for (int i = 0; i < 12; ++i) {
        int e = tid + i * 256;
        int r = e / 96, c8 = e % 96;
        uint2 v = src[e];
        dst[r * 193 + c8 * 2] = v.x;
        dst[r * 193 + c8 * 2 + 1] = v.y;
      }
    }
    __syncthreads();
    float d00 = 0.f, d01 = 0.f, d10 = 0.f, d11 = 0.f;
    const u32* qa = QsU + r0 * 193;
    const u32* qb = QsU + r1 * 193;
    const u32* ka = KsU + s0 * 193;
    const u32* kb = KsU + s1 * 193;
#pragma unroll 8
    for (int kk = 0; kk < 192; ++kk) {
      float2 a0 = upk(qa[kk]), a1 = upk(qb[kk]);
      float2 b0 = upk(ka[kk]), b1 = upk(kb[kk]);
      d00 += a0.x * b0.x + a0.y * b0.y;
      d01 += a0.x * b1.x + a0.y * b1.y;
      d10 += a1.x * b0.x + a1.y * b0.y;
      d11 += a1.x * b1.x + a1.y * b1.y;
    }
    d00 *= scale; d01 *= scale; d10 *= scale; d11 *= scale;
    float t0 = fmaxf(d00, d01), t1 = fmaxf(d10, d11);
#pragma unroll
    for (int mk = 8; mk; mk >>= 1) {
      t0 = fmaxf(t0, __shfl_xor(t0, mk));
      t1 = fmaxf(t1, __shfl_xor(t1, mk));
    }
    float nm0 = fmaxf(m0, t0), nm1 = fmaxf(m1, t1);
    float e0 = __expf(d00 - nm0) + __expf(d01 - nm0);
    float e1 = __expf(d10 - nm1) + __expf(d11 - nm1);
#pragma unroll
    for (int mk = 8; mk; mk >>= 1) {
      e0 += __shfl_xor(e0, mk);
      e1 += __shfl_xor(e1, mk);
    }
    l0 = l0 * __expf(m0 - nm0) + e0; m0 = nm0;
    l1 = l1 * __expf(m1 - nm1) + e1; m1 = nm1;
  }
  if (tx == 0) {
    stats[(size_t)bh * 1024 + o0 + r0] = make_float2(m0, 1.f / l0);
    stats[(size_t)bh * 1024 + o0 + r1] = make_float2(m1, 1.f / l1);
  }
}

// ---------------- att2 accumulate (transposed gather): own=keys, stream=queries,
// stats indexed by STREAM rows. out[own][dd] = sum_m A[m,own]*v[m][dd]
__global__ __launch_bounds__(256) void att_accum2(
    const u16* __restrict__ own, const u16* __restrict__ stream_x,
    const u16* __restrict__ vv, const float2* __restrict__ stats,
    u16* __restrict__ xall, float scale) {
  __shared__ u16 Own[32 * 386];
  __shared__ u16 Str[32 * 386];
  __shared__ float P[32 * 33];
  const int tid = threadIdx.x;
  const int tx = tid & 15, ty = tid >> 4;
  const int bh = blockIdx.y, o0 = blockIdx.x * 32;
  {
    const uint2* src = (const uint2*)(own + ((size_t)bh * 1024 + o0) * 384);
    u32* dst = (u32*)Own;
#pragma unroll
    for (int i = 0; i < 12; ++i) {
      int e = tid + i * 256;
      int r = e / 96, c8 = e % 96;
      uint2 v = src[e];
      dst[r * 193 + c8 * 2] = v.x;
      dst[r * 193 + c8 * 2 + 1] = v.y;
    }
  }
  const int r0 = ty * 2, r1 = r0 + 1, s0 = tx * 2, s1 = s0 + 1;
  float acc[2][12][2] = {};
  const u32* OwnU = (const u32*)Own;
  const u32* StrU = (const u32*)Str;
  const u32* vbase = (const u32*)(vv + (size_t)bh * 1024 * 384);
  for (int st = 0; st < 32; ++st) {
    __syncthreads();
    {
      const uint2* src = (const uint2*)(stream_x + ((size_t)bh * 1024 + st * 32) * 384);
      u32* dst = (u32*)Str;
#pragma unroll
      for (int i = 0; i < 12; ++i) {
        int e = tid + i * 256;
        int r = e / 96, c8 = e % 96;
        uint2 v = src[e];
        dst[r * 193 + c8 * 2] = v.x;
        dst[r * 193 + c8 * 2 + 1] = v.y;
      }
    }
    float2 sm0 = stats[(size_t)bh * 1024 + st * 32 + s0];
    float2 sm1 = stats[(size_t)bh * 1024 + st * 32 + s1];
    __syncthreads();
    float d00 = 0.f, d01 = 0.f, d10 = 0.f, d11 = 0.f;
    const u32* qa = OwnU + r0 * 193;
    const u32* qb = OwnU + r1 * 193;
    const u32* ka = StrU + s0 * 193;
    const u32* kb = StrU + s1 * 193;
#pragma unroll 8
    for (int kk = 0; kk < 192; ++kk) {
      float2 a0 = upk(qa[kk]), a1 = upk(qb[kk]);
      float2 b0 = upk(ka[kk]), b1 = upk(kb[kk]);
      d00 += a0.x * b0.x + a0.y * b0.y;
      d01 += a0.x * b1.x + a0.y * b1.y;
      d10 += a1.x * b0.x + a1.y * b0.y;
      d11 += a1.x * b1.x + a1.y * b1.y;
    }
    d00 *= scale; d01 *= scale; d10 *= scale; d11 *= scale;
    float p00 = __expf(d00 - sm0.x) * sm0.y;
    float p01 = __expf(d01 - sm1.x) * sm1.y;
    float p10 = __expf(d10 - sm0.x) * sm0.y;
    float p11 = __expf(d11 - sm1.x) * sm1.y;
    P[r0 * 33 + s0] = p00;
    P[r0 * 33 + s1] = p01;
    P[r1 * 33 + s0] = p10;
    P[r1 * 33 + s1] = p11;
    __syncthreads();
    const u32* vt = vbase + (size_t)(st * 32) * 192;
#pragma unroll 1
    for (int s = 0; s < 32; ++s) {
      float p0 = P[r0 * 33 + s];
      float p1 = P[r1 * 33 + s];
      const u32* vr = vt + (size_t)s * 192;
#pragma unroll
      for (int ii = 0; ii < 12; ++ii) {
        float2 vf = upk(vr[tx + 16 * ii]);
        acc[0][ii][0] += p0 * vf.x;
        acc[0][ii][1] += p0 * vf.y;
        acc[1][ii][0] += p1 * vf.x;
        acc[1][ii][1] += p1 * vf.y;
      }
    }
  }
  const int b = bh / 3, chb2 = 192 + (bh % 3) * 192;  // u32 offset: chans 384 + head*384
  u32* outU = (u32*)xall;
#pragma unroll
  for (int rr = 0; rr < 2; ++rr) {
    int row = o0 + ty * 2 + rr;
    size_t base = (size_t)(b * 1024 + row) * 768 + chb2;
#pragma unroll
    for (int ii = 0; ii < 12; ++ii) {
      outU[base + tx + 16 * ii] = pk2(acc[rr][ii][0], acc[rr][ii][1]);
    }
  }
}

// ---------------- IWT: xall (B,1024,1536) -> y (B,4096,384)
__global__ __launch_bounds__(256) void iwt_y(const u16* __restrict__ xall, u16* __restrict__ y) {
  const int blk = blockIdx.x;
  const int b = blk >> 10, pos = blk & 1023;
  const int i = pos >> 5, j = pos & 31;
  const u16* xr = xall + (size_t)(b * 1024 + pos) * 1536;
  u16* yb = y + (size_t)b * 4096 * 384;
  const int p00 = (i * 2) * 64 + j * 2;
  for (int c = threadIdx.x; c < 384; c += 256) {
    float g1 = 0.5f * b2f(xr[c]);
    float g2 = 0.5f * b2f(xr[c + 384]);
    float g3 = 0.5f * b2f(xr[c + 768]);
    float g4 = 0.5f * b2f(xr[c + 1152]);
    yb[(size_t)p00 * 384 + c]        = f2b(g1 - g2 - g3 + g4);
    yb[(size_t)(p00 + 64) * 384 + c] = f2b(g1 - g2 + g3 - g4);
    yb[(size_t)(p00 + 1) * 384 + c]  = f2b(g1 + g2 - g3 - g4);
    yb[(size_t)(p00 + 65) * 384 + c] = f2b(g1 + g2 + g3 + g4);
  }
}

extern "C" void kernel_launch(void* const* d_in, const int* in_sizes, int n_in,
                              void* d_out, int out_size, void* d_ws, size_t ws_size,
                              hipStream_t stream) {
  (void)in_sizes; (void)n_in; (void)out_size; (void)ws_size;
  const float* sf      = (const float*)d_in[0];
  const float* wf      = (const float*)d_in[1];
  const float* q_w     = (const float*)d_in[2];
  const float* q_b     = (const float*)d_in[3];
  const float* q_ln_w  = (const float*)d_in[4];
  const float* q_ln_b  = (const float*)d_in[5];
  const float* kv_w    = (const float*)d_in[6];
  const float* kv_b    = (const float*)d_in[7];
  const float* kv_ln_w = (const float*)d_in[8];
  const float* kv_ln_b = (const float*)d_in[9];
  const float* out_w   = (const float*)d_in[10];
  const float* out_b   = (const float*)d_in[11];
  float* out = (float*)d_out;

  // ---- workspace layout (bytes), ~168 MiB peak with phase aliasing ----
  char* p = (char*)d_ws;
  float* A  = (float*)p; p += 50331648;   // t_sf f32 (B,4096,384); later k1/v1/k2
  float* B1 = (float*)p; p += 50331648;   // t_wf chans 0..383 f32; later xall
  u16*   B2 = (u16*)p;   p += 25165824;   // t_wf chans 384..767 bf16; later y
  float* q1 = (float*)p; p += 12582912;   // (B,1024,384) f32
  u16*   q2 = (u16*)p;   p += 18874368;   // (B*3,1024,384) bf16
  u16*   v2 = (u16*)p;   p += 18874368;   // (B*3,1024,384) bf16
  float2* stats2 = (float2*)p;            // 24576 entries
  // aliases into A (t_sf dead after dwt_sf):
  float* k1 = A;                             // 12,582,912 B
  u16*   v1 = (u16*)((char*)A + 12582912);   //  6,291,456 B
  u16*   k2 = (u16*)((char*)A + 18874368);   // 18,874,368 B  (total 37.7MB <= 50.3MB)
  // aliases (dead after dwt_wf_split):
  u16* xall = (u16*)B1;   // 25,165,824 B <= 50.3MB
  u16* y    = B2;         // 25,165,824 B == B2 size

  const int M = 8 * 4096;

  // projections + LN (att1 score chain stays f32)
  gemm_bias<float, float><<<dim3(6, M / 64), 256, 0, stream>>>(sf, q_w, q_b, A, 384);
  ln_inplace<float><<<M, 256, 0, stream>>>(A, q_ln_w, q_ln_b, 384);
  gemm_bias<float, float><<<dim3(6, M / 64), 256, 0, stream>>>(wf, kv_w, kv_b, B1, 384);
  gemm_bias<float, u16><<<dim3(6, M / 64), 256, 0, stream>>>(wf, kv_w + 384 * 384, kv_b + 384, B2, 384);
  ln_wf_split<<<M, 256, 0, stream>>>(B1, B2, kv_ln_w, kv_ln_b);

  // DWT (order matters: dwt_sf reads A before k1/v1/k2 overwrite it)
  dwt_sf<<<8192, 256, 0, stream>>>(A, q1, q2);
  dwt_wf_split<<<8192, 256, 0, stream>>>(B1, B2, k1, k2, v1, v2);

  // att1: f32 flash (scale=1, huge scores need f32)
  flash_att1<<<dim3(64, 8), 256, 0, stream>>>(q1, k1, v1, xall);

  // att2: bf16 two-pass (scaled scores tolerate bf16)
  att_stats<<<dim3(32, 24), 256, 0, stream>>>(q2, k2, stats2, SCALE2);
  att_accum2<<<dim3(32, 24), 256, 0, stream>>>(k2, q2, v2, stats2, xall, SCALE2);

  // IWT + output projection
  iwt_y<<<8192, 256, 0, stream>>>(xall, y);
  gemm_bias<u16, float><<<dim3(6, M / 64), 256, 0, stream>>>(y, out_w, out_b, out, 384);
}

// Round 3
// 1570.293 us; speedup vs baseline: 2.0245x; 2.0245x over previous
//
#include <hip/hip_runtime.h>
#include <hip/hip_bf16.h>

typedef unsigned short u16;
typedef unsigned int u32;
typedef __attribute__((ext_vector_type(8))) short short8;   // 8 bf16 (4 VGPRs)
typedef __attribute__((ext_vector_type(4))) float f32x4;    // MFMA C/D

#define MFMA_BF16(A, B, C) __builtin_amdgcn_mfma_f32_16x16x32_bf16(A, B, C, 0, 0, 0)

#define SCALE2 0.08838834764831845f
#define LNEPS 1e-5f

__device__ __forceinline__ float b2f(u16 u) {
  return __uint_as_float(((u32)u) << 16);
}
__device__ __forceinline__ u16 f2b(float f) {
  u32 x = __float_as_uint(f);
  return (u16)((x + 0x7fffu + ((x >> 16) & 1u)) >> 16);  // RNE
}
__device__ __forceinline__ float ldf(const float* p) { return *p; }
__device__ __forceinline__ float ldf(const u16* p) { return b2f(*p); }
__device__ __forceinline__ void stf(float* p, float v) { *p = v; }
__device__ __forceinline__ void stf(u16* p, float v) { *p = f2b(v); }

// ---------------- GEMM: out[m][n] = sum_k X[m][k]*W[n][k] + bias[n]; K=384 fixed
template <typename TX, typename TO>
__global__ __launch_bounds__(256) void gemm_bias(
    const TX* __restrict__ X, const float* __restrict__ W,
    const float* __restrict__ bias, TO* __restrict__ out, int N) {
  __shared__ float As[32][68];
  __shared__ float Bs[32][68];
  const int tid = threadIdx.x;
  const int tx = tid & 15, ty = tid >> 4;
  const int m0 = blockIdx.y * 64, n0 = blockIdx.x * 64;
  float acc[4][4] = {};
  for (int kt = 0; kt < 384; kt += 32) {
#pragma unroll
    for (int i = 0; i < 8; ++i) {
      int e = tid + i * 256;
      int m = e >> 5, k = e & 31;
      As[k][m] = ldf(&X[(size_t)(m0 + m) * 384 + kt + k]);
    }
#pragma unroll
    for (int i = 0; i < 8; ++i) {
      int e = tid + i * 256;
      int nn = e >> 5, k = e & 31;
      Bs[k][nn] = W[(size_t)(n0 + nn) * 384 + kt + k];
    }
    __syncthreads();
#pragma unroll
    for (int kk = 0; kk < 32; ++kk) {
      float4 av = *(const float4*)&As[kk][ty * 4];
      float4 bv = *(const float4*)&Bs[kk][tx * 4];
      acc[0][0] += av.x * bv.x; acc[0][1] += av.x * bv.y; acc[0][2] += av.x * bv.z; acc[0][3] += av.x * bv.w;
      acc[1][0] += av.y * bv.x; acc[1][1] += av.y * bv.y; acc[1][2] += av.y * bv.z; acc[1][3] += av.y * bv.w;
      acc[2][0] += av.z * bv.x; acc[2][1] += av.z * bv.y; acc[2][2] += av.z * bv.z; acc[2][3] += av.z * bv.w;
      acc[3][0] += av.w * bv.x; acc[3][1] += av.w * bv.y; acc[3][2] += av.w * bv.z; acc[3][3] += av.w * bv.w;
    }
    __syncthreads();
  }
#pragma unroll
  for (int r = 0; r < 4; ++r) {
    int m = m0 + ty * 4 + r;
#pragma unroll
    for (int c = 0; c < 4; ++c) {
      int nn = n0 + tx * 4 + c;
      stf(&out[(size_t)m * N + nn], acc[r][c] + bias[nn]);
    }
  }
}

// ---------------- row LayerNorm, in place (templated storage)
template <typename T>
__global__ __launch_bounds__(256) void ln_inplace(
    T* __restrict__ Tb, const float* __restrict__ w, const float* __restrict__ b, int N) {
  const int row = blockIdx.x, tid = threadIdx.x;
  T* Tr = Tb + (size_t)row * N;
  float vals[3];
  float s = 0.f, ss = 0.f;
  int nv = 0;
  for (int i = tid; i < N; i += 256) {
    float v = ldf(&Tr[i]);
    vals[nv++] = v;
    s += v; ss += v * v;
  }
#pragma unroll
  for (int mk = 32; mk; mk >>= 1) { s += __shfl_xor(s, mk); ss += __shfl_xor(ss, mk); }
  __shared__ float red[8];
  if ((tid & 63) == 0) { red[tid >> 6] = s; red[4 + (tid >> 6)] = ss; }
  __syncthreads();
  s = red[0] + red[1] + red[2] + red[3];
  ss = red[4] + red[5] + red[6] + red[7];
  float inv = 1.f / (float)N;
  float mean = s * inv;
  float var = fmaxf(ss * inv - mean * mean, 0.f);
  float rstd = rsqrtf(var + LNEPS);
  nv = 0;
  for (int i = tid; i < N; i += 256) {
    float v = (vals[nv++] - mean) * rstd * w[i] + b[i];
    stf(&Tr[i], v);
  }
}

// ---------------- LN over split storage: lo = f32 chans 0..383, hi = bf16 chans 384..767
__global__ __launch_bounds__(256) void ln_wf_split(
    float* __restrict__ lo, u16* __restrict__ hi,
    const float* __restrict__ w, const float* __restrict__ b) {
  const int row = blockIdx.x, tid = threadIdx.x;
  float* L = lo + (size_t)row * 384;
  u16* H = hi + (size_t)row * 384;
  float vals[3];
  float s = 0.f, ss = 0.f;
  int nv = 0;
  for (int i = tid; i < 768; i += 256) {
    float v = (i < 384) ? L[i] : b2f(H[i - 384]);
    vals[nv++] = v;
    s += v; ss += v * v;
  }
#pragma unroll
  for (int mk = 32; mk; mk >>= 1) { s += __shfl_xor(s, mk); ss += __shfl_xor(ss, mk); }
  __shared__ float red[8];
  if ((tid & 63) == 0) { red[tid >> 6] = s; red[4 + (tid >> 6)] = ss; }
  __syncthreads();
  s = red[0] + red[1] + red[2] + red[3];
  ss = red[4] + red[5] + red[6] + red[7];
  float mean = s * (1.f / 768.f);
  float var = fmaxf(ss * (1.f / 768.f) - mean * mean, 0.f);
  float rstd = rsqrtf(var + LNEPS);
  nv = 0;
  for (int i = tid; i < 768; i += 256) {
    float v = (vals[nv++] - mean) * rstd * w[i] + b[i];
    if (i < 384) L[i] = v; else H[i - 384] = f2b(v);
  }
}

// ---------------- DWT sf: t_sf f32 -> q1 split-bf16 (hi+lo), q2 bf16 (3 heads)
__global__ __launch_bounds__(256) void dwt_sf(
    const float* __restrict__ T, u16* __restrict__ q1h, u16* __restrict__ q1l,
    u16* __restrict__ q2) {
  const int blk = blockIdx.x;
  const int b = blk >> 10, pos = blk & 1023;
  const int i = pos >> 5, j = pos & 31;
  const int p00 = (i * 2) * 64 + j * 2;
  const float* base = T + (size_t)b * 4096 * 384;
  for (int ch = threadIdx.x; ch < 384; ch += 256) {
    float a  = base[(size_t)p00 * 384 + ch];
    float cc = base[(size_t)(p00 + 1) * 384 + ch];
    float bb = base[(size_t)(p00 + 64) * 384 + ch];
    float dd = base[(size_t)(p00 + 65) * 384 + ch];
    float s0 = 0.5f * ( a + bb + cc + dd);
    float s1 = 0.5f * (-a - bb + cc + dd);
    float s2 = 0.5f * (-a + bb - cc + dd);
    float s3 = 0.5f * ( a - bb - cc + dd);
    size_t po = (size_t)(b * 1024 + pos) * 384 + ch;
    u16 h = f2b(s0);
    q1h[po] = h;
    q1l[po] = f2b(s0 - b2f(h));
    q2[(size_t)((b * 3 + 0) * 1024 + pos) * 384 + ch] = f2b(s1);
    q2[(size_t)((b * 3 + 1) * 1024 + pos) * 384 + ch] = f2b(s2);
    q2[(size_t)((b * 3 + 2) * 1024 + pos) * 384 + ch] = f2b(s3);
  }
}

// ---------------- DWT wf (split input): lo f32, hi bf16 -> k1 split-bf16, v1, k2, v2
__global__ __launch_bounds__(256) void dwt_wf_split(
    const float* __restrict__ lo, const u16* __restrict__ hi,
    u16* __restrict__ k1h, u16* __restrict__ k1l, u16* __restrict__ v1,
    u16* __restrict__ k2, u16* __restrict__ v2) {
  const int blk = blockIdx.x;
  const int b = blk >> 10, pos = blk & 1023;
  const int i = pos >> 5, j = pos & 31;
  const int p00 = (i * 2) * 64 + j * 2;
  for (int ch = threadIdx.x; ch < 768; ch += 256) {
    float a, bb, cc, dd;
    if (ch < 384) {
      const float* base = lo + (size_t)b * 4096 * 384;
      a  = base[(size_t)p00 * 384 + ch];
      cc = base[(size_t)(p00 + 1) * 384 + ch];
      bb = base[(size_t)(p00 + 64) * 384 + ch];
      dd = base[(size_t)(p00 + 65) * 384 + ch];
    } else {
      const u16* base = hi + (size_t)b * 4096 * 384;
      int c = ch - 384;
      a  = b2f(base[(size_t)p00 * 384 + c]);
      cc = b2f(base[(size_t)(p00 + 1) * 384 + c]);
      bb = b2f(base[(size_t)(p00 + 64) * 384 + c]);
      dd = b2f(base[(size_t)(p00 + 65) * 384 + c]);
    }
    float s0 = 0.5f * ( a + bb + cc + dd);
    float s1 = 0.5f * (-a - bb + cc + dd);
    float s2 = 0.5f * (-a + bb - cc + dd);
    float s3 = 0.5f * ( a - bb - cc + dd);
    if (ch < 384) {
      size_t po = (size_t)(b * 1024 + pos) * 384 + ch;
      u16 h = f2b(s0);
      k1h[po] = h;
      k1l[po] = f2b(s0 - b2f(h));
      v1[po] = f2b(s2);
      k2[(size_t)((b * 3 + 1) * 1024 + pos) * 384 + ch] = f2b(s1);
      v2[(size_t)((b * 3 + 1) * 1024 + pos) * 384 + ch] = f2b(s3);
    } else {
      int c = ch - 384;
      k2[(size_t)((b * 3 + 0) * 1024 + pos) * 384 + c] = f2b(s0);
      k2[(size_t)((b * 3 + 2) * 1024 + pos) * 384 + c] = f2b(s1);
      v2[(size_t)((b * 3 + 0) * 1024 + pos) * 384 + c] = f2b(s2);
      v2[(size_t)((b * 3 + 2) * 1024 + pos) * 384 + c] = f2b(s3);
    }
  }
}

// ---------------- transpose [bh][1024][384] -> [bh][384][1024] (for V as MFMA B-operand)
__global__ __launch_bounds__(256) void transpose_rm(
    const u16* __restrict__ in, u16* __restrict__ out) {
  __shared__ u16 T[64][65];
  const int tid = threadIdx.x;
  const int bh = blockIdx.z, r0 = blockIdx.y * 64, c0 = blockIdx.x * 64;
  const u16* ip = in + ((size_t)bh * 1024 + r0) * 384 + c0;
  for (int i = tid; i < 2048; i += 256) {
    int r = i >> 5, c2 = i & 31;
    u32 v = *(const u32*)(ip + (size_t)r * 384 + c2 * 2);
    T[c2 * 2][r] = (u16)v;
    T[c2 * 2 + 1][r] = (u16)(v >> 16);
  }
  __syncthreads();
  u16* op = out + ((size_t)bh * 384 + c0) * 1024 + r0;
  for (int i = tid; i < 2048; i += 256) {
    int c = i >> 5, r2 = i & 31;
    u32 v = (u32)T[c][r2 * 2] | ((u32)T[c][r2 * 2 + 1] << 16);
    *(u32*)(op + (size_t)c * 1024 + r2 * 2) = v;
  }
}

// ---------------- MFMA attention pass 1: per-query-row max & sumexp.
// Own = queries (rows of S). 4 waves: (Mi = w&1 rows, Ni = w>>1 col-half).
// SPLIT: hi/lo bf16 3-product f32-precision scores.
template <int SPLIT>
__global__ __launch_bounds__(256) void att_stats_mfma(
    const u16* __restrict__ qh, const u16* __restrict__ qlo,
    const u16* __restrict__ kh, const u16* __restrict__ klo,
    float2* __restrict__ stats, float scale) {
  const int tid = threadIdx.x;
  const int w = tid >> 6, lane = tid & 63;
  const int t = lane & 15, qd = lane >> 4;
  const int Mi = w & 1, Ni = w >> 1;
  const int bh = blockIdx.y, o0 = blockIdx.x * 32;
  short8 Ah[12], Al[12];
  {
    const short* s1 = (const short*)qh + ((size_t)bh * 1024 + o0 + Mi * 16 + t) * 384 + qd * 8;
#pragma unroll
    for (int ks = 0; ks < 12; ++ks) Ah[ks] = *(const short8*)(s1 + ks * 32);
    if (SPLIT) {
      const short* s2 = (const short*)qlo + ((size_t)bh * 1024 + o0 + Mi * 16 + t) * 384 + qd * 8;
#pragma unroll
      for (int ks = 0; ks < 12; ++ks) Al[ks] = *(const short8*)(s2 + ks * 32);
    }
  }
  float m[4], l[4];
#pragma unroll
  for (int r = 0; r < 4; ++r) { m[r] = -1e30f; l[r] = 0.f; }
  for (int st = 0; st < 32; ++st) {
    const short* kb  = (const short*)kh  + ((size_t)bh * 1024 + st * 32 + Ni * 16 + t) * 384 + qd * 8;
    const short* kb2 = (const short*)klo + ((size_t)bh * 1024 + st * 32 + Ni * 16 + t) * 384 + qd * 8;
    f32x4 S = {0.f, 0.f, 0.f, 0.f};
#pragma unroll
    for (int ks = 0; ks < 12; ++ks) {
      short8 Bh = *(const short8*)(kb + ks * 32);
      S = MFMA_BF16(Ah[ks], Bh, S);
      if (SPLIT) {
        short8 Bl = *(const short8*)(kb2 + ks * 32);
        S = MFMA_BF16(Al[ks], Bh, S);
        S = MFMA_BF16(Ah[ks], Bl, S);
      }
    }
#pragma unroll
    for (int r = 0; r < 4; ++r) {
      float s = S[r] * scale;
      float mx = s;
#pragma unroll
      for (int mk = 1; mk < 16; mk <<= 1) mx = fmaxf(mx, __shfl_xor(mx, mk));
      float nm = fmaxf(m[r], mx);
      float e = __expf(s - nm);
#pragma unroll
      for (int mk = 1; mk < 16; mk <<= 1) e += __shfl_xor(e, mk);
      l[r] = l[r] * __expf(m[r] - nm) + e;
      m[r] = nm;
    }
  }
  __shared__ float2 comb[2][32];
  if (t == 0) {
#pragma unroll
    for (int r = 0; r < 4; ++r) comb[Ni][Mi * 16 + qd * 4 + r] = make_float2(m[r], l[r]);
  }
  __syncthreads();
  if (tid < 32) {
    float2 a = comb[0][tid], b = comb[1][tid];
    float nm = fmaxf(a.x, b.x);
    float ll = a.y * __expf(a.x - nm) + b.y * __expf(b.x - nm);
    stats[(size_t)bh * 1024 + o0 + tid] = make_float2(nm, 1.f / ll);
  }
}

// ---------------- MFMA attention pass 2: out[own][d] = sum_str P * Vt[d][str]
// COLSTATS=0 (att1): own=q rows, stats by own row.  out chans [0,384)
// COLSTATS=1 (att2): own=k rows, stream=queries, stats by stream col. chans 384+head*384
template <int SPLIT, int COLSTATS>
__global__ __launch_bounds__(256) void att_accum_mfma(
    const u16* __restrict__ ownh, const u16* __restrict__ ownl,
    const u16* __restrict__ strh, const u16* __restrict__ strl,
    const u16* __restrict__ vt, const float2* __restrict__ stats,
    u16* __restrict__ xall, float scale) {
  __shared__ u16 Pl[32 * 40];
  const int tid = threadIdx.x;
  const int w = tid >> 6, lane = tid & 63;
  const int t = lane & 15, qd = lane >> 4;
  const int Mi = w & 1, Ni = w >> 1;
  const int bh = blockIdx.y, o0 = blockIdx.x * 32;
  short8 Ah[12], Al[12];
  {
    const short* s1 = (const short*)ownh + ((size_t)bh * 1024 + o0 + Mi * 16 + t) * 384 + qd * 8;
#pragma unroll
    for (int ks = 0; ks < 12; ++ks) Ah[ks] = *(const short8*)(s1 + ks * 32);
    if (SPLIT) {
      const short* s2 = (const short*)ownl + ((size_t)bh * 1024 + o0 + Mi * 16 + t) * 384 + qd * 8;
#pragma unroll
      for (int ks = 0; ks < 12; ++ks) Al[ks] = *(const short8*)(s2 + ks * 32);
    }
  }
  float sm[4], sr[4];
  if (!COLSTATS) {
#pragma unroll
    for (int r = 0; r < 4; ++r) {
      float2 s = stats[(size_t)bh * 1024 + o0 + Mi * 16 + qd * 4 + r];
      sm[r] = s.x; sr[r] = s.y;
    }
  }
  f32x4 acc[12];
#pragma unroll
  for (int i = 0; i < 12; ++i) acc[i] = (f32x4){0.f, 0.f, 0.f, 0.f};
  const int Nb = Ni * 12;
  for (int st = 0; st < 32; ++st) {
    const short* kb  = (const short*)strh + ((size_t)bh * 1024 + st * 32 + Ni * 16 + t) * 384 + qd * 8;
    const short* kb2 = (const short*)strl + ((size_t)bh * 1024 + st * 32 + Ni * 16 + t) * 384 + qd * 8;
    f32x4 S = {0.f, 0.f, 0.f, 0.f};
#pragma unroll
    for (int ks = 0; ks < 12; ++ks) {
      short8 Bh = *(const short8*)(kb + ks * 32);
      S = MFMA_BF16(Ah[ks], Bh, S);
      if (SPLIT) {
        short8 Bl = *(const short8*)(kb2 + ks * 32);
        S = MFMA_BF16(Al[ks], Bh, S);
        S = MFMA_BF16(Ah[ks], Bl, S);
      }
    }
    float2 cs;
    if (COLSTATS) cs = stats[(size_t)bh * 1024 + st * 32 + Ni * 16 + t];
#pragma unroll
    for (int r = 0; r < 4; ++r) {
      float p = COLSTATS ? __expf(S[r] * scale - cs.x) * cs.y
                         : __expf(S[r] * scale - sm[r]) * sr[r];
      Pl[(Mi * 16 + qd * 4 + r) * 40 + Ni * 16 + t] = f2b(p);
    }
    __syncthreads();
    short8 Pa = *(const short8*)&Pl[(Mi * 16 + t) * 40 + qd * 8];
#pragma unroll
    for (int nj = 0; nj < 12; ++nj) {
      const short* vb = (const short*)vt + ((size_t)bh * 384 + (Nb + nj) * 16 + t) * 1024 + st * 32 + qd * 8;
      short8 Bv = *(const short8*)vb;
      acc[nj] = MFMA_BF16(Pa, Bv, acc[nj]);
    }
    __syncthreads();
  }
  int b_out, off;
  if (COLSTATS) { b_out = bh / 3; off = (1 + bh % 3) * 384; } else { b_out = bh; off = 0; }
#pragma unroll
  for (int nj = 0; nj < 12; ++nj) {
#pragma unroll
    for (int r = 0; r < 4; ++r) {
      int row = o0 + Mi * 16 + qd * 4 + r;
      int d = (Nb + nj) * 16 + t;
      xall[((size_t)b_out * 1024 + row) * 1536 + off + d] = f2b(acc[nj][r]);
    }
  }
}

// ---------------- IWT: xall (B,1024,1536) -> y (B,4096,384)
__global__ __launch_bounds__(256) void iwt_y(const u16* __restrict__ xall, u16* __restrict__ y) {
  const int blk = blockIdx.x;
  const int b = blk >> 10, pos = blk & 1023;
  const int i = pos >> 5, j = pos & 31;
  const u16* xr = xall + (size_t)(b * 1024 + pos) * 1536;
  u16* yb = y + (size_t)b * 4096 * 384;
  const int p00 = (i * 2) * 64 + j * 2;
  for (int c = threadIdx.x; c < 384; c += 256) {
    float g1 = 0.5f * b2f(xr[c]);
    float g2 = 0.5f * b2f(xr[c + 384]);
    float g3 = 0.5f * b2f(xr[c + 768]);
    float g4 = 0.5f * b2f(xr[c + 1152]);
    yb[(size_t)p00 * 384 + c]        = f2b(g1 - g2 - g3 + g4);
    yb[(size_t)(p00 + 64) * 384 + c] = f2b(g1 - g2 + g3 - g4);
    yb[(size_t)(p00 + 1) * 384 + c]  = f2b(g1 + g2 - g3 - g4);
    yb[(size_t)(p00 + 65) * 384 + c] = f2b(g1 + g2 + g3 + g4);
  }
}

extern "C" void kernel_launch(void* const* d_in, const int* in_sizes, int n_in,
                              void* d_out, int out_size, void* d_ws, size_t ws_size,
                              hipStream_t stream) {
  (void)in_sizes; (void)n_in; (void)out_size; (void)ws_size;
  const float* sf      = (const float*)d_in[0];
  const float* wf      = (const float*)d_in[1];
  const float* q_w     = (const float*)d_in[2];
  const float* q_b     = (const float*)d_in[3];
  const float* q_ln_w  = (const float*)d_in[4];
  const float* q_ln_b  = (const float*)d_in[5];
  const float* kv_w    = (const float*)d_in[6];
  const float* kv_b    = (const float*)d_in[7];
  const float* kv_ln_w = (const float*)d_in[8];
  const float* kv_ln_b = (const float*)d_in[9];
  const float* out_w   = (const float*)d_in[10];
  const float* out_b   = (const float*)d_in[11];
  float* out = (float*)d_out;

  // ---- workspace layout, ~168 MiB peak with phase aliasing ----
  char* p = (char*)d_ws;
  float* A  = (float*)p; p += 50331648;   // t_sf f32; later k1h|k1l|v1|k2|v1t
  float* B1 = (float*)p; p += 50331648;   // t_wf lo f32; later xall
  u16*   B2 = (u16*)p;   p += 25165824;   // t_wf hi bf16; later v2t; later y
  u16* q1h = (u16*)p; p += 6291456;       // (8,1024,384) bf16 hi
  u16* q1l = (u16*)p; p += 6291456;       // lo
  u16* q2  = (u16*)p; p += 18874368;      // (24,1024,384) bf16
  u16* v2  = (u16*)p; p += 18874368;      // (24,1024,384) bf16 row-major
  float2* stats1 = (float2*)p; p += 65536;    // 8192 float2
  float2* stats2 = (float2*)p;                // 24576 float2
  // aliases inside A (t_sf dead after dwt_sf):
  u16* k1h = (u16*)A;                 // 3,145,728 elems each
  u16* k1l = k1h + 3145728;
  u16* v1  = k1l + 3145728;
  u16* k2  = v1 + 3145728;            // 9,437,184 elems
  u16* v1t = k2 + 9437184;            // (8,384,1024) -> 44.0MB total <= 50.3MB
  u16* xall = (u16*)B1;               // (8,1024,1536) 25.2MB <= 50.3MB
  u16* v2t = B2;                      // (24,384,1024) 18.9MB <= 25.2MB (t_wf-hi dead)
  u16* y   = B2;                      // (8,4096,384) 25.2MB (v2t dead by IWT time)

  const int M = 8 * 4096;

  // projections + LN (att1 score chain stays f32)
  gemm_bias<float, float><<<dim3(6, M / 64), 256, 0, stream>>>(sf, q_w, q_b, A, 384);
  ln_inplace<float><<<M, 256, 0, stream>>>(A, q_ln_w, q_ln_b, 384);
  gemm_bias<float, float><<<dim3(6, M / 64), 256, 0, stream>>>(wf, kv_w, kv_b, B1, 384);
  gemm_bias<float, u16><<<dim3(6, M / 64), 256, 0, stream>>>(wf, kv_w + 384 * 384, kv_b + 384, B2, 384);
  ln_wf_split<<<M, 256, 0, stream>>>(B1, B2, kv_ln_w, kv_ln_b);

  // DWT (dwt_sf must read A before k1/v1/k2/v1t overwrite it)
  dwt_sf<<<8192, 256, 0, stream>>>(A, q1h, q1l, q2);
  dwt_wf_split<<<8192, 256, 0, stream>>>(B1, B2, k1h, k1l, v1, k2, v2);

  // V transposes for MFMA B-operand layout
  transpose_rm<<<dim3(6, 16, 8), 256, 0, stream>>>(v1, v1t);
  transpose_rm<<<dim3(6, 16, 24), 256, 0, stream>>>(v2, v2t);  // overwrites dead t_wf-hi

  // attention (MFMA): stats then accumulate
  att_stats_mfma<1><<<dim3(32, 8), 256, 0, stream>>>(q1h, q1l, k1h, k1l, stats1, 1.0f);
  att_stats_mfma<0><<<dim3(32, 24), 256, 0, stream>>>(q2, q2, k2, k2, stats2, SCALE2);
  att_accum_mfma<1, 0><<<dim3(32, 8), 256, 0, stream>>>(q1h, q1l, k1h, k1l, v1t, stats1, xall, 1.0f);
  att_accum_mfma<0, 1><<<dim3(32, 24), 256, 0, stream>>>(k2, k2, q2, q2, v2t, stats2, xall, SCALE2);

  // IWT + output projection
  iwt_y<<<8192, 256, 0, stream>>>(xall, y);
  gemm_bias<u16, float><<<dim3(6, M / 64), 256, 0, stream>>>(y, out_w, out_b, out, 384);
}

// Round 4
// 1093.218 us; speedup vs baseline: 2.9080x; 1.4364x over previous
//
#include <hip/hip_runtime.h>
#include <hip/hip_bf16.h>

typedef unsigned short u16;
typedef unsigned int u32;
typedef __attribute__((ext_vector_type(8))) short short8;   // 8 bf16 (4 VGPRs)
typedef __attribute__((ext_vector_type(4))) float f32x4;    // MFMA C/D

#define MFMA_BF16(A, B, C) __builtin_amdgcn_mfma_f32_16x16x32_bf16(A, B, C, 0, 0, 0)

#define SCALE2 0.08838834764831845f
#define LNEPS 1e-5f

__device__ __forceinline__ float b2f(u16 u) {
  return __uint_as_float(((u32)u) << 16);
}
__device__ __forceinline__ u16 f2b(float f) {
  u32 x = __float_as_uint(f);
  return (u16)((x + 0x7fffu + ((x >> 16) & 1u)) >> 16);  // RNE
}
__device__ __forceinline__ float ldf(const float* p) { return *p; }
__device__ __forceinline__ float ldf(const u16* p) { return b2f(*p); }
__device__ __forceinline__ void stf(float* p, float v) { *p = v; }
__device__ __forceinline__ void stf(u16* p, float v) { *p = f2b(v); }

// async global(16B/lane) -> LDS(base + lane*16). dst must be wave-uniform.
__device__ __forceinline__ void glds16(const u16* g, u16* l) {
  __builtin_amdgcn_global_load_lds(
      (const __attribute__((address_space(1))) u32*)(uintptr_t)(g),
      (__attribute__((address_space(3))) u32*)(uintptr_t)(l), 16, 0, 0);
}
// wait all vmem (drains global_load_lds + prefetched reg loads)
#define WAIT_VM0() __builtin_amdgcn_s_waitcnt(0x0F70)

// ---------------- MFMA GEMM: out[m][n] = sum_k X[m][k]*W[n][k] + bias[n]
// K=384, N=384. Block 128Mx128N, 4 waves (2x2 of 64x64). SPLIT: hi/lo bf16
// 3-product f32-precision (X must be float).
template <int SPLIT, typename TX, typename TO>
__global__ __launch_bounds__(256) void gemm_mfma(
    const TX* __restrict__ X, const float* __restrict__ W,
    const float* __restrict__ bias, TO* __restrict__ out) {
  __shared__ __align__(16) u16 AH[128 * 40];
  __shared__ __align__(16) u16 BH[128 * 40];
  __shared__ __align__(16) u16 AL[SPLIT ? 128 * 40 : 8];
  __shared__ __align__(16) u16 BL[SPLIT ? 128 * 40 : 8];
  const int tid = threadIdx.x;
  const int w = tid >> 6, lane = tid & 63;
  const int t = lane & 15, qd = lane >> 4;
  const int wm = w & 1, wn = w >> 1;
  const int m0 = blockIdx.y * 128, n0 = blockIdx.x * 128;
  f32x4 acc[4][4];
#pragma unroll
  for (int i = 0; i < 4; ++i)
#pragma unroll
    for (int j = 0; j < 4; ++j) acc[i][j] = (f32x4){0.f, 0.f, 0.f, 0.f};
  for (int kt = 0; kt < 384; kt += 32) {
    // stage A (128x32) and B (128x32) with f32->bf16 convert
#pragma unroll
    for (int rep = 0; rep < 4; ++rep) {
      int e = tid + rep * 256;
      int m = e >> 3, k4 = (e & 7) * 4;
      if constexpr (sizeof(TX) == 4) {
        float4 v = *(const float4*)(X + (size_t)(m0 + m) * 384 + kt + k4);
        u16 h0 = f2b(v.x), h1 = f2b(v.y), h2 = f2b(v.z), h3 = f2b(v.w);
        u32 hp0 = (u32)h0 | ((u32)h1 << 16), hp1 = (u32)h2 | ((u32)h3 << 16);
        *(uint2*)&AH[m * 40 + k4] = make_uint2(hp0, hp1);
        if (SPLIT) {
          u16 l0 = f2b(v.x - b2f(h0)), l1 = f2b(v.y - b2f(h1));
          u16 l2 = f2b(v.z - b2f(h2)), l3 = f2b(v.w - b2f(h3));
          *(uint2*)&AL[m * 40 + k4] =
              make_uint2((u32)l0 | ((u32)l1 << 16), (u32)l2 | ((u32)l3 << 16));
        }
      } else {
        uint2 raw = *(const uint2*)(X + (size_t)(m0 + m) * 384 + kt + k4);
        *(uint2*)&AH[m * 40 + k4] = raw;
      }
      float4 wv = *(const float4*)(W + (size_t)(n0 + m) * 384 + kt + k4);
      u16 wh0 = f2b(wv.x), wh1 = f2b(wv.y), wh2 = f2b(wv.z), wh3 = f2b(wv.w);
      *(uint2*)&BH[m * 40 + k4] =
          make_uint2((u32)wh0 | ((u32)wh1 << 16), (u32)wh2 | ((u32)wh3 << 16));
      if (SPLIT) {
        u16 wl0 = f2b(wv.x - b2f(wh0)), wl1 = f2b(wv.y - b2f(wh1));
        u16 wl2 = f2b(wv.z - b2f(wh2)), wl3 = f2b(wv.w - b2f(wh3));
        *(uint2*)&BL[m * 40 + k4] =
            make_uint2((u32)wl0 | ((u32)wl1 << 16), (u32)wl2 | ((u32)wl3 << 16));
      }
    }
    __syncthreads();
    short8 af[4], bf[4], al[4], bl[4];
#pragma unroll
    for (int mi = 0; mi < 4; ++mi) {
      af[mi] = *(const short8*)&AH[(wm * 64 + mi * 16 + t) * 40 + qd * 8];
      bf[mi] = *(const short8*)&BH[(wn * 64 + mi * 16 + t) * 40 + qd * 8];
      if (SPLIT) {
        al[mi] = *(const short8*)&AL[(wm * 64 + mi * 16 + t) * 40 + qd * 8];
        bl[mi] = *(const short8*)&BL[(wn * 64 + mi * 16 + t) * 40 + qd * 8];
      }
    }
#pragma unroll
    for (int mi = 0; mi < 4; ++mi)
#pragma unroll
      for (int ni = 0; ni < 4; ++ni) {
        acc[mi][ni] = MFMA_BF16(af[mi], bf[ni], acc[mi][ni]);
        if (SPLIT) {
          acc[mi][ni] = MFMA_BF16(al[mi], bf[ni], acc[mi][ni]);
          acc[mi][ni] = MFMA_BF16(af[mi], bl[ni], acc[mi][ni]);
        }
      }
    __syncthreads();
  }
#pragma unroll
  for (int ni = 0; ni < 4; ++ni) {
    int n = n0 + wn * 64 + ni * 16 + t;
    float bv = bias[n];
#pragma unroll
    for (int mi = 0; mi < 4; ++mi)
#pragma unroll
      for (int r = 0; r < 4; ++r) {
        int m = m0 + wm * 64 + mi * 16 + qd * 4 + r;
        stf(&out[(size_t)m * 384 + n], acc[mi][ni][r] + bv);
      }
  }
}

// ---------------- row LayerNorm, in place (templated storage)
template <typename T>
__global__ __launch_bounds__(256) void ln_inplace(
    T* __restrict__ Tb, const float* __restrict__ w, const float* __restrict__ b, int N) {
  const int row = blockIdx.x, tid = threadIdx.x;
  T* Tr = Tb + (size_t)row * N;
  float vals[3];
  float s = 0.f, ss = 0.f;
  int nv = 0;
  for (int i = tid; i < N; i += 256) {
    float v = ldf(&Tr[i]);
    vals[nv++] = v;
    s += v; ss += v * v;
  }
#pragma unroll
  for (int mk = 32; mk; mk >>= 1) { s += __shfl_xor(s, mk); ss += __shfl_xor(ss, mk); }
  __shared__ float red[8];
  if ((tid & 63) == 0) { red[tid >> 6] = s; red[4 + (tid >> 6)] = ss; }
  __syncthreads();
  s = red[0] + red[1] + red[2] + red[3];
  ss = red[4] + red[5] + red[6] + red[7];
  float inv = 1.f / (float)N;
  float mean = s * inv;
  float var = fmaxf(ss * inv - mean * mean, 0.f);
  float rstd = rsqrtf(var + LNEPS);
  nv = 0;
  for (int i = tid; i < N; i += 256) {
    float v = (vals[nv++] - mean) * rstd * w[i] + b[i];
    stf(&Tr[i], v);
  }
}

// ---------------- LN over split storage: lo = f32 chans 0..383, hi = bf16 chans 384..767
__global__ __launch_bounds__(256) void ln_wf_split(
    float* __restrict__ lo, u16* __restrict__ hi,
    const float* __restrict__ w, const float* __restrict__ b) {
  const int row = blockIdx.x, tid = threadIdx.x;
  float* L = lo + (size_t)row * 384;
  u16* H = hi + (size_t)row * 384;
  float vals[3];
  float s = 0.f, ss = 0.f;
  int nv = 0;
  for (int i = tid; i < 768; i += 256) {
    float v = (i < 384) ? L[i] : b2f(H[i - 384]);
    vals[nv++] = v;
    s += v; ss += v * v;
  }
#pragma unroll
  for (int mk = 32; mk; mk >>= 1) { s += __shfl_xor(s, mk); ss += __shfl_xor(ss, mk); }
  __shared__ float red[8];
  if ((tid & 63) == 0) { red[tid >> 6] = s; red[4 + (tid >> 6)] = ss; }
  __syncthreads();
  s = red[0] + red[1] + red[2] + red[3];
  ss = red[4] + red[5] + red[6] + red[7];
  float mean = s * (1.f / 768.f);
  float var = fmaxf(ss * (1.f / 768.f) - mean * mean, 0.f);
  float rstd = rsqrtf(var + LNEPS);
  nv = 0;
  for (int i = tid; i < 768; i += 256) {
    float v = (vals[nv++] - mean) * rstd * w[i] + b[i];
    if (i < 384) L[i] = v; else H[i - 384] = f2b(v);
  }
}

// ---------------- DWT sf: t_sf f32 -> q1 split-bf16 (hi+lo), q2 bf16 (3 heads)
__global__ __launch_bounds__(256) void dwt_sf(
    const float* __restrict__ T, u16* __restrict__ q1h, u16* __restrict__ q1l,
    u16* __restrict__ q2) {
  const int blk = blockIdx.x;
  const int b = blk >> 10, pos = blk & 1023;
  const int i = pos >> 5, j = pos & 31;
  const int p00 = (i * 2) * 64 + j * 2;
  const float* base = T + (size_t)b * 4096 * 384;
  for (int ch = threadIdx.x; ch < 384; ch += 256) {
    float a  = base[(size_t)p00 * 384 + ch];
    float cc = base[(size_t)(p00 + 1) * 384 + ch];
    float bb = base[(size_t)(p00 + 64) * 384 + ch];
    float dd = base[(size_t)(p00 + 65) * 384 + ch];
    float s0 = 0.5f * ( a + bb + cc + dd);
    float s1 = 0.5f * (-a - bb + cc + dd);
    float s2 = 0.5f * (-a + bb - cc + dd);
    float s3 = 0.5f * ( a - bb - cc + dd);
    size_t po = (size_t)(b * 1024 + pos) * 384 + ch;
    u16 h = f2b(s0);
    q1h[po] = h;
    q1l[po] = f2b(s0 - b2f(h));
    q2[(size_t)((b * 3 + 0) * 1024 + pos) * 384 + ch] = f2b(s1);
    q2[(size_t)((b * 3 + 1) * 1024 + pos) * 384 + ch] = f2b(s2);
    q2[(size_t)((b * 3 + 2) * 1024 + pos) * 384 + ch] = f2b(s3);
  }
}

// ---------------- DWT wf (split input): lo f32, hi bf16 -> k1 split-bf16, v1, k2, v2
__global__ __launch_bounds__(256) void dwt_wf_split(
    const float* __restrict__ lo, const u16* __restrict__ hi,
    u16* __restrict__ k1h, u16* __restrict__ k1l, u16* __restrict__ v1,
    u16* __restrict__ k2, u16* __restrict__ v2) {
  const int blk = blockIdx.x;
  const int b = blk >> 10, pos = blk & 1023;
  const int i = pos >> 5, j = pos & 31;
  const int p00 = (i * 2) * 64 + j * 2;
  for (int ch = threadIdx.x; ch < 768; ch += 256) {
    float a, bb, cc, dd;
    if (ch < 384) {
      const float* base = lo + (size_t)b * 4096 * 384;
      a  = base[(size_t)p00 * 384 + ch];
      cc = base[(size_t)(p00 + 1) * 384 + ch];
      bb = base[(size_t)(p00 + 64) * 384 + ch];
      dd = base[(size_t)(p00 + 65) * 384 + ch];
    } else {
      const u16* base = hi + (size_t)b * 4096 * 384;
      int c = ch - 384;
      a  = b2f(base[(size_t)p00 * 384 + c]);
      cc = b2f(base[(size_t)(p00 + 1) * 384 + c]);
      bb = b2f(base[(size_t)(p00 + 64) * 384 + c]);
      dd = b2f(base[(size_t)(p00 + 65) * 384 + c]);
    }
    float s0 = 0.5f * ( a + bb + cc + dd);
    float s1 = 0.5f * (-a - bb + cc + dd);
    float s2 = 0.5f * (-a + bb - cc + dd);
    float s3 = 0.5f * ( a - bb - cc + dd);
    if (ch < 384) {
      size_t po = (size_t)(b * 1024 + pos) * 384 + ch;
      u16 h = f2b(s0);
      k1h[po] = h;
      k1l[po] = f2b(s0 - b2f(h));
      v1[po] = f2b(s2);
      k2[(size_t)((b * 3 + 1) * 1024 + pos) * 384 + ch] = f2b(s1);
      v2[(size_t)((b * 3 + 1) * 1024 + pos) * 384 + ch] = f2b(s3);
    } else {
      int c = ch - 384;
      k2[(size_t)((b * 3 + 0) * 1024 + pos) * 384 + c] = f2b(s0);
      k2[(size_t)((b * 3 + 2) * 1024 + pos) * 384 + c] = f2b(s1);
      v2[(size_t)((b * 3 + 0) * 1024 + pos) * 384 + c] = f2b(s2);
      v2[(size_t)((b * 3 + 2) * 1024 + pos) * 384 + c] = f2b(s3);
    }
  }
}

// ---------------- transpose [bh][1024][384] -> [bh][384][1024]
__global__ __launch_bounds__(256) void transpose_rm(
    const u16* __restrict__ in, u16* __restrict__ out) {
  __shared__ u16 T[64][65];
  const int tid = threadIdx.x;
  const int bh = blockIdx.z, r0 = blockIdx.y * 64, c0 = blockIdx.x * 64;
  const u16* ip = in + ((size_t)bh * 1024 + r0) * 384 + c0;
  for (int i = tid; i < 2048; i += 256) {
    int r = i >> 5, c2 = i & 31;
    u32 v = *(const u32*)(ip + (size_t)r * 384 + c2 * 2);
    T[c2 * 2][r] = (u16)v;
    T[c2 * 2 + 1][r] = (u16)(v >> 16);
  }
  __syncthreads();
  u16* op = out + ((size_t)bh * 384 + c0) * 1024 + r0;
  for (int i = tid; i < 2048; i += 256) {
    int c = i >> 5, r2 = i & 31;
    u32 v = (u32)T[c][r2 * 2] | ((u32)T[c][r2 * 2 + 1] << 16);
    *(u32*)(op + (size_t)c * 1024 + r2 * 2) = v;
  }
}

// ---------------- att2 stats (plain bf16): per query row m/l over all keys.
// Block: 16 own rows; per iter 64 stream rows; wave w scores sub-tile w from
// its private LDS region (no barriers in the loop).
__global__ __launch_bounds__(256) void att2_stats(
    const u16* __restrict__ q, const u16* __restrict__ k,
    float2* __restrict__ stats, float scale) {
  __shared__ __align__(16) u16 Str[4 * 6144];  // 48 KB
  __shared__ float2 comb[4][16];
  const int tid = threadIdx.x, w = tid >> 6, lane = tid & 63;
  const int t = lane & 15, qd = lane >> 4;
  const int bh = blockIdx.y, o0 = blockIdx.x * 16;
  short8 Ah[12];
  {
    const u16* qp = q + ((size_t)bh * 1024 + o0 + t) * 384 + qd * 8;
#pragma unroll
    for (int ks = 0; ks < 12; ++ks) Ah[ks] = *(const short8*)(qp + ks * 32);
  }
  float m[4] = {-1e30f, -1e30f, -1e30f, -1e30f}, l[4] = {0.f, 0.f, 0.f, 0.f};
  u16* myStr = &Str[w * 6144];
  for (int st = 0; st < 16; ++st) {
    const u16* kp = k + ((size_t)bh * 1024 + st * 64 + w * 16 + t) * 384 + qd * 8;
#pragma unroll
    for (int ks = 0; ks < 12; ++ks) glds16(kp + ks * 32, myStr + ks * 512);
    WAIT_VM0();
    f32x4 S0 = {0.f, 0.f, 0.f, 0.f}, S1 = {0.f, 0.f, 0.f, 0.f};
#pragma unroll
    for (int ks = 0; ks < 12; ks += 2) {
      short8 B0 = *(const short8*)(myStr + ks * 512 + lane * 8);
      short8 B1 = *(const short8*)(myStr + (ks + 1) * 512 + lane * 8);
      S0 = MFMA_BF16(Ah[ks], B0, S0);
      S1 = MFMA_BF16(Ah[ks + 1], B1, S1);
    }
#pragma unroll
    for (int r = 0; r < 4; ++r) {
      float s = (S0[r] + S1[r]) * scale;
      float mx = s;
#pragma unroll
      for (int mk = 1; mk < 16; mk <<= 1) mx = fmaxf(mx, __shfl_xor(mx, mk));
      float nm = fmaxf(m[r], mx);
      float e = __expf(s - nm);
#pragma unroll
      for (int mk = 1; mk < 16; mk <<= 1) e += __shfl_xor(e, mk);
      l[r] = l[r] * __expf(m[r] - nm) + e;
      m[r] = nm;
    }
  }
  if (t == 0) {
#pragma unroll
    for (int r = 0; r < 4; ++r) comb[w][qd * 4 + r] = make_float2(m[r], l[r]);
  }
  __syncthreads();
  if (tid < 16) {
    float nm = comb[0][tid].x;
#pragma unroll
    for (int ww = 1; ww < 4; ++ww) nm = fmaxf(nm, comb[ww][tid].x);
    float ll = 0.f;
#pragma unroll
    for (int ww = 0; ww < 4; ++ww) ll += comb[ww][tid].y * __expf(comb[ww][tid].x - nm);
    stats[(size_t)bh * 1024 + o0 + tid] = make_float2(nm, 1.f / ll);
  }
}

// ---------------- att2 accumulate (transposed gather): own=keys, stream=queries,
// stats indexed by stream rows. One barrier/iter; P double-buffered; V prefetched.
__global__ __launch_bounds__(256) void att2_accum(
    const u16* __restrict__ own, const u16* __restrict__ str,
    const u16* __restrict__ vt, const float2* __restrict__ stats,
    u16* __restrict__ xall, float scale) {
  __shared__ __align__(16) u16 Str[4 * 6144];  // 48 KB
  __shared__ __align__(16) u16 P[2][16 * 72];  // double-buffered 4.5 KB
  const int tid = threadIdx.x, w = tid >> 6, lane = tid & 63;
  const int t = lane & 15, qd = lane >> 4;
  const int bh = blockIdx.y, o0 = blockIdx.x * 16;
  short8 Ah[12];
  {
    const u16* op = own + ((size_t)bh * 1024 + o0 + t) * 384 + qd * 8;
#pragma unroll
    for (int ks = 0; ks < 12; ++ks) Ah[ks] = *(const short8*)(op + ks * 32);
  }
  f32x4 acc[6];
#pragma unroll
  for (int i = 0; i < 6; ++i) acc[i] = (f32x4){0.f, 0.f, 0.f, 0.f};
  u16* myStr = &Str[w * 6144];
  const u16* vbase = vt + ((size_t)bh * 384 + w * 96 + t) * 1024;
  for (int st = 0; st < 16; ++st) {
    const int pb = st & 1;
    const u16* sp = str + ((size_t)bh * 1024 + st * 64 + w * 16 + t) * 384 + qd * 8;
#pragma unroll
    for (int ks = 0; ks < 12; ++ks) glds16(sp + ks * 32, myStr + ks * 512);
    short8 Vr[12];
#pragma unroll
    for (int nj = 0; nj < 6; ++nj) {
      Vr[nj * 2]     = *(const short8*)(vbase + (size_t)nj * 16 * 1024 + st * 64 + qd * 8);
      Vr[nj * 2 + 1] = *(const short8*)(vbase + (size_t)nj * 16 * 1024 + st * 64 + 32 + qd * 8);
    }
    float2 cs = stats[(size_t)bh * 1024 + st * 64 + w * 16 + t];
    WAIT_VM0();
    f32x4 S0 = {0.f, 0.f, 0.f, 0.f}, S1 = {0.f, 0.f, 0.f, 0.f};
#pragma unroll
    for (int ks = 0; ks < 12; ks += 2) {
      short8 B0 = *(const short8*)(myStr + ks * 512 + lane * 8);
      short8 B1 = *(const short8*)(myStr + (ks + 1) * 512 + lane * 8);
      S0 = MFMA_BF16(Ah[ks], B0, S0);
      S1 = MFMA_BF16(Ah[ks + 1], B1, S1);
    }
#pragma unroll
    for (int r = 0; r < 4; ++r) {
      float p = __expf((S0[r] + S1[r]) * scale - cs.x) * cs.y;
      P[pb][(qd * 4 + r) * 72 + w * 16 + t] = f2b(p);
    }
    __syncthreads();
    short8 Pa0 = *(const short8*)&P[pb][t * 72 + qd * 8];
    short8 Pa1 = *(const short8*)&P[pb][t * 72 + 32 + qd * 8];
#pragma unroll
    for (int nj = 0; nj < 6; ++nj) {
      acc[nj] = MFMA_BF16(Pa0, Vr[nj * 2], acc[nj]);
      acc[nj] = MFMA_BF16(Pa1, Vr[nj * 2 + 1], acc[nj]);
    }
  }
  const int b_out = bh / 3, off = (1 + bh % 3) * 384;
#pragma unroll
  for (int nj = 0; nj < 6; ++nj)
#pragma unroll
    for (int r = 0; r < 4; ++r) {
      int row = o0 + qd * 4 + r;
      int d = w * 96 + nj * 16 + t;
      xall[((size_t)b_out * 1024 + row) * 1536 + off + d] = f2b(acc[nj][r]);
    }
}

// ---------------- att1 stats (split hi/lo, f32-precision scores, scale=1).
// Per iter 32 stream rows. Waves 0,1: hh+lh chains + softmax state for sub w.
// Waves 2,3: hl chain (str-lo in regs) -> partial to LDS.
__global__ __launch_bounds__(256) void att1_stats(
    const u16* __restrict__ qh, const u16* __restrict__ ql,
    const u16* __restrict__ kh, const u16* __restrict__ kl,
    float2* __restrict__ stats) {
  __shared__ __align__(16) u16 StrH[2 * 6144];  // 24 KB
  __shared__ float Sp[2][16][17];
  __shared__ float2 comb[2][16];
  const int tid = threadIdx.x, w = tid >> 6, lane = tid & 63;
  const int t = lane & 15, qd = lane >> 4;
  const int bh = blockIdx.y, o0 = blockIdx.x * 16;
  const int ss = w & 1;
  const bool scorer = (w < 2);
  short8 Ah[12], R2[12];  // R2: q-lo (scorers, persistent) / str-lo (w23, per-iter)
  {
    const u16* qp = qh + ((size_t)bh * 1024 + o0 + t) * 384 + qd * 8;
#pragma unroll
    for (int ks = 0; ks < 12; ++ks) Ah[ks] = *(const short8*)(qp + ks * 32);
    if (scorer) {
      const u16* qp2 = ql + ((size_t)bh * 1024 + o0 + t) * 384 + qd * 8;
#pragma unroll
      for (int ks = 0; ks < 12; ++ks) R2[ks] = *(const short8*)(qp2 + ks * 32);
    }
  }
  float m[4] = {-1e30f, -1e30f, -1e30f, -1e30f}, l[4] = {0.f, 0.f, 0.f, 0.f};
  for (int st = 0; st < 32; ++st) {
    if (scorer) {
      const u16* kp = kh + ((size_t)bh * 1024 + st * 32 + w * 16 + t) * 384 + qd * 8;
#pragma unroll
      for (int ks = 0; ks < 12; ++ks) glds16(kp + ks * 32, &StrH[w * 6144 + ks * 512]);
    } else {
      const u16* kp = kl + ((size_t)bh * 1024 + st * 32 + ss * 16 + t) * 384 + qd * 8;
#pragma unroll
      for (int ks = 0; ks < 12; ++ks) R2[ks] = *(const short8*)(kp + ks * 32);
    }
    __syncthreads();  // StrH ready (drains glds)
    f32x4 S0 = {0.f, 0.f, 0.f, 0.f}, S1 = {0.f, 0.f, 0.f, 0.f};
    const u16* sb = &StrH[ss * 6144];
    if (scorer) {
#pragma unroll
      for (int ks = 0; ks < 12; ++ks) {
        short8 Bh = *(const short8*)(sb + ks * 512 + lane * 8);
        S0 = MFMA_BF16(Ah[ks], Bh, S0);
        S1 = MFMA_BF16(R2[ks], Bh, S1);
      }
    } else {
#pragma unroll
      for (int ks = 0; ks < 12; ks += 2) {
        S0 = MFMA_BF16(Ah[ks], R2[ks], S0);
        S1 = MFMA_BF16(Ah[ks + 1], R2[ks + 1], S1);
      }
#pragma unroll
      for (int r = 0; r < 4; ++r) Sp[ss][qd * 4 + r][t] = S0[r] + S1[r];
    }
    __syncthreads();  // Sp ready
    if (scorer) {
#pragma unroll
      for (int r = 0; r < 4; ++r) {
        float s = S0[r] + S1[r] + Sp[w][qd * 4 + r][t];
        float mx = s;
#pragma unroll
        for (int mk = 1; mk < 16; mk <<= 1) mx = fmaxf(mx, __shfl_xor(mx, mk));
        float nm = fmaxf(m[r], mx);
        float e = __expf(s - nm);
#pragma unroll
        for (int mk = 1; mk < 16; mk <<= 1) e += __shfl_xor(e, mk);
        l[r] = l[r] * __expf(m[r] - nm) + e;
        m[r] = nm;
      }
    }
  }
  if (scorer && t == 0) {
#pragma unroll
    for (int r = 0; r < 4; ++r) comb[w][qd * 4 + r] = make_float2(m[r], l[r]);
  }
  __syncthreads();
  if (tid < 16) {
    float2 a = comb[0][tid], b = comb[1][tid];
    float nm = fmaxf(a.x, b.x);
    float ll = a.y * __expf(a.x - nm) + b.y * __expf(b.x - nm);
    stats[(size_t)bh * 1024 + o0 + tid] = make_float2(nm, 1.f / ll);
  }
}

// ---------------- att1 accumulate (split scores, standard attn direction).
__global__ __launch_bounds__(256) void att1_accum(
    const u16* __restrict__ qh, const u16* __restrict__ ql,
    const u16* __restrict__ kh, const u16* __restrict__ kl,
    const u16* __restrict__ vt, const float2* __restrict__ stats,
    u16* __restrict__ xall) {
  __shared__ __align__(16) u16 StrH[2 * 6144];  // 24 KB
  __shared__ float Sp[2][16][17];
  __shared__ __align__(16) u16 P[16 * 40];
  const int tid = threadIdx.x, w = tid >> 6, lane = tid & 63;
  const int t = lane & 15, qd = lane >> 4;
  const int bh = blockIdx.y, o0 = blockIdx.x * 16;
  const int ss = w & 1;
  const bool scorer = (w < 2);
  short8 Ah[12], R2[12];
  float sm[4], sr[4];
  {
    const u16* qp = qh + ((size_t)bh * 1024 + o0 + t) * 384 + qd * 8;
#pragma unroll
    for (int ks = 0; ks < 12; ++ks) Ah[ks] = *(const short8*)(qp + ks * 32);
    if (scorer) {
      const u16* qp2 = ql + ((size_t)bh * 1024 + o0 + t) * 384 + qd * 8;
#pragma unroll
      for (int ks = 0; ks < 12; ++ks) R2[ks] = *(const short8*)(qp2 + ks * 32);
#pragma unroll
      for (int r = 0; r < 4; ++r) {
        float2 s2 = stats[(size_t)bh * 1024 + o0 + qd * 4 + r];
        sm[r] = s2.x; sr[r] = s2.y;
      }
    }
  }
  f32x4 acc[6];
#pragma unroll
  for (int i = 0; i < 6; ++i) acc[i] = (f32x4){0.f, 0.f, 0.f, 0.f};
  const u16* vbase = vt + ((size_t)bh * 384 + w * 96 + t) * 1024;
  for (int st = 0; st < 32; ++st) {
    if (scorer) {
      const u16* kp = kh + ((size_t)bh * 1024 + st * 32 + w * 16 + t) * 384 + qd * 8;
#pragma unroll
      for (int ks = 0; ks < 12; ++ks) glds16(kp + ks * 32, &StrH[w * 6144 + ks * 512]);
    } else {
      const u16* kp = kl + ((size_t)bh * 1024 + st * 32 + ss * 16 + t) * 384 + qd * 8;
#pragma unroll
      for (int ks = 0; ks < 12; ++ks) R2[ks] = *(const short8*)(kp + ks * 32);
    }
    short8 Vr[6];
#pragma unroll
    for (int nj = 0; nj < 6; ++nj)
      Vr[nj] = *(const short8*)(vbase + (size_t)nj * 16 * 1024 + st * 32 + qd * 8);
    __syncthreads();  // #1: StrH ready
    f32x4 S0 = {0.f, 0.f, 0.f, 0.f}, S1 = {0.f, 0.f, 0.f, 0.f};
    const u16* sb = &StrH[ss * 6144];
    if (scorer) {
#pragma unroll
      for (int ks = 0; ks < 12; ++ks) {
        short8 Bh = *(const short8*)(sb + ks * 512 + lane * 8);
        S0 = MFMA_BF16(Ah[ks], Bh, S0);
        S1 = MFMA_BF16(R2[ks], Bh, S1);
      }
    } else {
#pragma unroll
      for (int ks = 0; ks < 12; ks += 2) {
        S0 = MFMA_BF16(Ah[ks], R2[ks], S0);
        S1 = MFMA_BF16(Ah[ks + 1], R2[ks + 1], S1);
      }
#pragma unroll
      for (int r = 0; r < 4; ++r) Sp[ss][qd * 4 + r][t] = S0[r] + S1[r];
    }
    __syncthreads();  // #2: Sp ready
    if (scorer) {
#pragma unroll
      for (int r = 0; r < 4; ++r) {
        float s = S0[r] + S1[r] + Sp[w][qd * 4 + r][t];
        float p = __expf(s - sm[r]) * sr[r];
        P[(qd * 4 + r) * 40 + w * 16 + t] = f2b(p);
      }
    }
    __syncthreads();  // #3: P ready
    short8 Pa = *(const short8*)&P[t * 40 + qd * 8];
#pragma unroll
    for (int nj = 0; nj < 6; ++nj) acc[nj] = MFMA_BF16(Pa, Vr[nj], acc[nj]);
  }
#pragma unroll
  for (int nj = 0; nj < 6; ++nj)
#pragma unroll
    for (int r = 0; r < 4; ++r) {
      int row = o0 + qd * 4 + r;
      int d = w * 96 + nj * 16 + t;
      xall[((size_t)bh * 1024 + row) * 1536 + d] = f2b(acc[nj][r]);
    }
}

// ---------------- IWT: xall (B,1024,1536) -> y (B,4096,384)
__global__ __launch_bounds__(256) void iwt_y(const u16* __restrict__ xall, u16* __restrict__ y) {
  const int blk = blockIdx.x;
  const int b = blk >> 10, pos = blk & 1023;
  const int i = pos >> 5, j = pos & 31;
  const u16* xr = xall + (size_t)(b * 1024 + pos) * 1536;
  u16* yb = y + (size_t)b * 4096 * 384;
  const int p00 = (i * 2) * 64 + j * 2;
  for (int c = threadIdx.x; c < 384; c += 256) {
    float g1 = 0.5f * b2f(xr[c]);
    float g2 = 0.5f * b2f(xr[c + 384]);
    float g3 = 0.5f * b2f(xr[c + 768]);
    float g4 = 0.5f * b2f(xr[c + 1152]);
    yb[(size_t)p00 * 384 + c]        = f2b(g1 - g2 - g3 + g4);
    yb[(size_t)(p00 + 64) * 384 + c] = f2b(g1 - g2 + g3 - g4);
    yb[(size_t)(p00 + 1) * 384 + c]  = f2b(g1 + g2 - g3 - g4);
    yb[(size_t)(p00 + 65) * 384 + c] = f2b(g1 + g2 + g3 + g4);
  }
}

extern "C" void kernel_launch(void* const* d_in, const int* in_sizes, int n_in,
                              void* d_out, int out_size, void* d_ws, size_t ws_size,
                              hipStream_t stream) {
  (void)in_sizes; (void)n_in; (void)out_size; (void)ws_size;
  const float* sf      = (const float*)d_in[0];
  const float* wf      = (const float*)d_in[1];
  const float* q_w     = (const float*)d_in[2];
  const float* q_b     = (const float*)d_in[3];
  const float* q_ln_w  = (const float*)d_in[4];
  const float* q_ln_b  = (const float*)d_in[5];
  const float* kv_w    = (const float*)d_in[6];
  const float* kv_b    = (const float*)d_in[7];
  const float* kv_ln_w = (const float*)d_in[8];
  const float* kv_ln_b = (const float*)d_in[9];
  const float* out_w   = (const float*)d_in[10];
  const float* out_b   = (const float*)d_in[11];
  float* out = (float*)d_out;

  // ---- workspace layout, ~168 MiB peak with phase aliasing ----
  char* p = (char*)d_ws;
  float* A  = (float*)p; p += 50331648;   // t_sf f32; later k1h|k1l|v1|k2|v1t
  float* B1 = (float*)p; p += 50331648;   // t_wf lo f32; later xall
  u16*   B2 = (u16*)p;   p += 25165824;   // t_wf hi bf16; later v2t; later y
  u16* q1h = (u16*)p; p += 6291456;       // (8,1024,384) bf16 hi
  u16* q1l = (u16*)p; p += 6291456;       // lo
  u16* q2  = (u16*)p; p += 18874368;      // (24,1024,384) bf16
  u16* v2  = (u16*)p; p += 18874368;      // (24,1024,384) bf16 row-major
  float2* stats1 = (float2*)p; p += 65536;    // 8192 float2
  float2* stats2 = (float2*)p;                // 24576 float2
  // aliases inside A (t_sf dead after dwt_sf):
  u16* k1h = (u16*)A;
  u16* k1l = k1h + 3145728;
  u16* v1  = k1l + 3145728;
  u16* k2  = v1 + 3145728;
  u16* v1t = k2 + 9437184;            // (8,384,1024)
  u16* xall = (u16*)B1;               // (8,1024,1536)
  u16* v2t = B2;                      // (24,384,1024)
  u16* y   = B2;                      // (8,4096,384)

  // projections (MFMA) + LN; att1 score chain stays f32-precision via split
  gemm_mfma<1, float, float><<<dim3(3, 256), 256, 0, stream>>>(sf, q_w, q_b, A);
  ln_inplace<float><<<32768, 256, 0, stream>>>(A, q_ln_w, q_ln_b, 384);
  gemm_mfma<1, float, float><<<dim3(3, 256), 256, 0, stream>>>(wf, kv_w, kv_b, B1);
  gemm_mfma<0, float, u16><<<dim3(3, 256), 256, 0, stream>>>(wf, kv_w + 384 * 384, kv_b + 384, B2);
  ln_wf_split<<<32768, 256, 0, stream>>>(B1, B2, kv_ln_w, kv_ln_b);

  // DWT (dwt_sf must read A before k1/v1/k2/v1t overwrite it)
  dwt_sf<<<8192, 256, 0, stream>>>(A, q1h, q1l, q2);
  dwt_wf_split<<<8192, 256, 0, stream>>>(B1, B2, k1h, k1l, v1, k2, v2);

  // V transposes for MFMA B-operand layout
  transpose_rm<<<dim3(6, 16, 8), 256, 0, stream>>>(v1, v1t);
  transpose_rm<<<dim3(6, 16, 24), 256, 0, stream>>>(v2, v2t);  // overwrites dead t_wf-hi

  // attention
  att1_stats<<<dim3(64, 8), 256, 0, stream>>>(q1h, q1l, k1h, k1l, stats1);
  att2_stats<<<dim3(64, 24), 256, 0, stream>>>(q2, k2, stats2, SCALE2);
  att1_accum<<<dim3(64, 8), 256, 0, stream>>>(q1h, q1l, k1h, k1l, v1t, stats1, xall);
  att2_accum<<<dim3(64, 24), 256, 0, stream>>>(k2, q2, v2t, stats2, xall, SCALE2);

  // IWT + output projection (MFMA)
  iwt_y<<<8192, 256, 0, stream>>>(xall, y);
  gemm_mfma<0, u16, float><<<dim3(3, 256), 256, 0, stream>>>(y, out_w, out_b, out);
}